// Round 1
// baseline (299.983 us; speedup 1.0000x reference)
//
#include <hip/hip_runtime.h>

// Magnus2: x_{n+1} = E_n x_n with a shared 2x2 E_n across the batch.
// v2: (1) E-build fused into the single-block scan (no E round-trip, one
// fewer launch), (2) out kernel reshaped like fillBuffer: 2048 blocks x
// 4 rows each, 32 float4 nontemporal stores per thread.

struct M2 { float a, b, c, d; };

typedef float f32x4 __attribute__((ext_vector_type(4)));

__device__ __forceinline__ M2 mmul(const M2& X, const M2& Y) {
    // X * Y (X applied after Y)
    M2 r;
    r.a = X.a * Y.a + X.b * Y.c;
    r.b = X.a * Y.b + X.b * Y.d;
    r.c = X.c * Y.a + X.d * Y.c;
    r.d = X.c * Y.b + X.d * Y.d;
    return r;
}

// Build E_n exactly as the previous (verified) e_kernel did.
__device__ __forceinline__ M2 build_E(const float* __restrict__ t, int n,
                                      float w2, float g0, float ga, float wd,
                                      int uc) {
    float t0 = t[n], t1 = t[n + 1];
    float dt = t1 - t0;
    float tm = t0 + dt * 0.5f;

    float gam0 = g0 * (1.0f + ga * sinf(wd * t0));
    float gamm = g0 * (1.0f + ga * sinf(wd * tm));
    float gam1 = g0 * (1.0f + ga * sinf(wd * t1));

    // Omega = A_mid*dt (+ dt^2/12 * [A0,A1]); [A0,A1] = [[0,d],[w2*d,0]], d=g0-g1
    float Oa = 0.0f;
    float Ob = dt;
    float Oc = -w2 * dt;
    float Od = -gamm * dt;
    if (uc) {
        float k = dt * dt * (1.0f / 12.0f);
        float del = gam0 - gam1;
        Ob += k * del;
        Oc += k * (w2 * del);
    }

    // expm of 2x2
    float m   = 0.5f * (Oa + Od);
    float det = Oa * Od - Ob * Oc;
    float delta = m * m - det;
    float s = sqrtf(fabsf(delta));
    bool pos = delta >= 0.0f;
    bool small_ = s < 1e-6f;
    float s_safe = small_ ? 1.0f : s;
    float cosl = pos ? coshf(s) : cosf(s);
    float sn   = pos ? sinhf(s_safe) : sinf(s_safe);
    float sinch = small_ ? 1.0f : sn / s_safe;
    float em = expf(m);

    M2 E;
    E.a = em * (cosl + sinch * (Oa - m));
    E.b = em * (sinch * Ob);
    E.c = em * (sinch * Oc);
    E.d = em * (cosl + sinch * (Od - m));
    return E;
}

// ---------------- Kernel 0: fused E-build + prefix-product scan ----------------
// P[0] = I; P[n] = E_{n-1} ... E_0 for n in [1, T-1]. Requires T <= 8192.
__global__ __launch_bounds__(1024) void escan_kernel(const float* __restrict__ t,
                                                     const float* __restrict__ p_w2,
                                                     const float* __restrict__ p_g0,
                                                     const float* __restrict__ p_ga,
                                                     const float* __restrict__ p_wd,
                                                     const int* __restrict__ p_uc,
                                                     float4* __restrict__ P, int T) {
    __shared__ float4 lds[1024];
    const int j = threadIdx.x;
    const int base = j * 8;

    float w2 = *p_w2, g0 = *p_g0, ga = *p_ga, wd = *p_wd;
    int uc = *p_uc;

    // local inclusive chain over 8 consecutive matrices (identity-padded),
    // E built inline (no global round-trip)
    M2 S[8];
    #pragma unroll
    for (int mi = 0; mi < 8; ++mi) {
        int k = base + mi;
        M2 Mk;
        if (k < T - 1) {
            Mk = build_E(t, k, w2, g0, ga, wd, uc);
        } else {
            Mk.a = 1.0f; Mk.b = 0.0f; Mk.c = 0.0f; Mk.d = 1.0f;
        }
        S[mi] = (mi == 0) ? Mk : mmul(Mk, S[mi - 1]);
    }

    // block-wide inclusive scan of chunk products (newer-on-left combine)
    M2 acc = S[7];
    lds[j] = make_float4(acc.a, acc.b, acc.c, acc.d);
    for (int d = 1; d < 1024; d <<= 1) {
        __syncthreads();
        M2 prev;
        bool act = (j >= d);
        if (act) {
            float4 p = lds[j - d];
            prev.a = p.x; prev.b = p.y; prev.c = p.z; prev.d = p.w;
        }
        __syncthreads();
        if (act) {
            acc = mmul(acc, prev);
            lds[j] = make_float4(acc.a, acc.b, acc.c, acc.d);
        }
    }
    __syncthreads();

    // exclusive offset for this chunk
    M2 Bm;
    if (j == 0) { Bm.a = 1.0f; Bm.b = 0.0f; Bm.c = 0.0f; Bm.d = 1.0f; }
    else {
        float4 p = lds[j - 1];
        Bm.a = p.x; Bm.b = p.y; Bm.c = p.z; Bm.d = p.w;
    }

    if (j == 0) P[0] = make_float4(1.0f, 0.0f, 0.0f, 1.0f);
    #pragma unroll
    for (int mi = 0; mi < 8; ++mi) {
        int g = base + mi + 1;      // P index this slot produces
        if (g < T) {
            M2 r = mmul(S[mi], Bm);
            P[g] = make_float4(r.a, r.b, r.c, r.d);
        }
    }
}

// ---------------- Kernel 1: out[n] = P_n @ x0 — fill-shaped streaming store ----
// 4 consecutive rows per block: 128 KB contiguous writes/block, x0 L1-resident,
// nontemporal stores (output never re-read).
__global__ __launch_bounds__(256) void out_kernel(const float4* __restrict__ P,
                                                  const float* __restrict__ x0,
                                                  float* __restrict__ out,
                                                  int B, int T) {
    const int q = B >> 2;                            // float4 groups per row
    const float4* xr0 = (const float4*)x0;           // row 0 of x0
    const float4* xr1 = xr0 + q;                     // row 1 of x0
    const int n0 = blockIdx.x * 4;

    #pragma unroll
    for (int nn = 0; nn < 4; ++nn) {
        const int n = n0 + nn;
        if (n >= T) return;
        const float4 p = P[n];
        float4* o = (float4*)(out + (size_t)n * (size_t)(2 * B));
        for (int g = threadIdx.x; g < q; g += 256) {
            float4 u = xr0[g];
            float4 v = xr1[g];
            float4 r0, r1;
            r0.x = p.x * u.x + p.y * v.x;
            r0.y = p.x * u.y + p.y * v.y;
            r0.z = p.x * u.z + p.y * v.z;
            r0.w = p.x * u.w + p.y * v.w;
            r1.x = p.z * u.x + p.w * v.x;
            r1.y = p.z * u.y + p.w * v.y;
            r1.z = p.z * u.z + p.w * v.z;
            r1.w = p.z * u.w + p.w * v.w;
            __builtin_nontemporal_store(*(const f32x4*)&r0, (f32x4*)&o[g]);
            __builtin_nontemporal_store(*(const f32x4*)&r1, (f32x4*)&o[q + g]);
        }
    }
}

extern "C" void kernel_launch(void* const* d_in, const int* in_sizes, int n_in,
                              void* d_out, int out_size, void* d_ws, size_t ws_size,
                              hipStream_t stream) {
    const float* t   = (const float*)d_in[0];
    const float* x0  = (const float*)d_in[1];
    const float* w2  = (const float*)d_in[2];
    const float* g0  = (const float*)d_in[3];
    const float* ga  = (const float*)d_in[4];
    const float* wd  = (const float*)d_in[5];
    const int*   uc  = (const int*)d_in[6];

    const int T = in_sizes[0];          // 8192
    const int B = in_sizes[1] / 2;      // 4096

    float4* P = (float4*)d_ws;          // T float4 (128 KB)
    float* out = (float*)d_out;

    escan_kernel<<<1, 1024, 0, stream>>>(t, w2, g0, ga, wd, uc, P, T);
    out_kernel<<<(T + 3) / 4, 256, 0, stream>>>(P, x0, out, B, T);
}

// Round 2
// 284.237 us; speedup vs baseline: 1.0554x; 1.0554x over previous
//
#include <hip/hip_runtime.h>

// Magnus2: x_{n+1} = E_n x_n with a shared 2x2 E_n across the batch.
// v3: fused E-build+scan (1 block), out kernel: 2 rows/block, x0 loaded once
// per column-group and reused for both rows, plain float4 stores (NT reverted).

struct M2 { float a, b, c, d; };

__device__ __forceinline__ M2 mmul(const M2& X, const M2& Y) {
    // X * Y (X applied after Y)
    M2 r;
    r.a = X.a * Y.a + X.b * Y.c;
    r.b = X.a * Y.b + X.b * Y.d;
    r.c = X.c * Y.a + X.d * Y.c;
    r.d = X.c * Y.b + X.d * Y.d;
    return r;
}

// Build E_n exactly as the verified e_kernel did.
__device__ __forceinline__ M2 build_E(const float* __restrict__ t, int n,
                                      float w2, float g0, float ga, float wd,
                                      int uc) {
    float t0 = t[n], t1 = t[n + 1];
    float dt = t1 - t0;
    float tm = t0 + dt * 0.5f;

    float gam0 = g0 * (1.0f + ga * sinf(wd * t0));
    float gamm = g0 * (1.0f + ga * sinf(wd * tm));
    float gam1 = g0 * (1.0f + ga * sinf(wd * t1));

    // Omega = A_mid*dt (+ dt^2/12 * [A0,A1]); [A0,A1] = [[0,d],[w2*d,0]], d=g0-g1
    float Oa = 0.0f;
    float Ob = dt;
    float Oc = -w2 * dt;
    float Od = -gamm * dt;
    if (uc) {
        float k = dt * dt * (1.0f / 12.0f);
        float del = gam0 - gam1;
        Ob += k * del;
        Oc += k * (w2 * del);
    }

    // expm of 2x2
    float m   = 0.5f * (Oa + Od);
    float det = Oa * Od - Ob * Oc;
    float delta = m * m - det;
    float s = sqrtf(fabsf(delta));
    bool pos = delta >= 0.0f;
    bool small_ = s < 1e-6f;
    float s_safe = small_ ? 1.0f : s;
    float cosl = pos ? coshf(s) : cosf(s);
    float sn   = pos ? sinhf(s_safe) : sinf(s_safe);
    float sinch = small_ ? 1.0f : sn / s_safe;
    float em = expf(m);

    M2 E;
    E.a = em * (cosl + sinch * (Oa - m));
    E.b = em * (sinch * Ob);
    E.c = em * (sinch * Oc);
    E.d = em * (cosl + sinch * (Od - m));
    return E;
}

// ---------------- Kernel 0: fused E-build + prefix-product scan ----------------
// P[0] = I; P[n] = E_{n-1} ... E_0 for n in [1, T-1]. Requires T <= 8192.
__global__ __launch_bounds__(1024) void escan_kernel(const float* __restrict__ t,
                                                     const float* __restrict__ p_w2,
                                                     const float* __restrict__ p_g0,
                                                     const float* __restrict__ p_ga,
                                                     const float* __restrict__ p_wd,
                                                     const int* __restrict__ p_uc,
                                                     float4* __restrict__ P, int T) {
    __shared__ float4 lds[1024];
    const int j = threadIdx.x;
    const int base = j * 8;

    float w2 = *p_w2, g0 = *p_g0, ga = *p_ga, wd = *p_wd;
    int uc = *p_uc;

    // local inclusive chain over 8 consecutive matrices (identity-padded)
    M2 S[8];
    #pragma unroll
    for (int mi = 0; mi < 8; ++mi) {
        int k = base + mi;
        M2 Mk;
        if (k < T - 1) {
            Mk = build_E(t, k, w2, g0, ga, wd, uc);
        } else {
            Mk.a = 1.0f; Mk.b = 0.0f; Mk.c = 0.0f; Mk.d = 1.0f;
        }
        S[mi] = (mi == 0) ? Mk : mmul(Mk, S[mi - 1]);
    }

    // block-wide inclusive scan of chunk products (newer-on-left combine)
    M2 acc = S[7];
    lds[j] = make_float4(acc.a, acc.b, acc.c, acc.d);
    for (int d = 1; d < 1024; d <<= 1) {
        __syncthreads();
        M2 prev;
        bool act = (j >= d);
        if (act) {
            float4 p = lds[j - d];
            prev.a = p.x; prev.b = p.y; prev.c = p.z; prev.d = p.w;
        }
        __syncthreads();
        if (act) {
            acc = mmul(acc, prev);
            lds[j] = make_float4(acc.a, acc.b, acc.c, acc.d);
        }
    }
    __syncthreads();

    // exclusive offset for this chunk
    M2 Bm;
    if (j == 0) { Bm.a = 1.0f; Bm.b = 0.0f; Bm.c = 0.0f; Bm.d = 1.0f; }
    else {
        float4 p = lds[j - 1];
        Bm.a = p.x; Bm.b = p.y; Bm.c = p.z; Bm.d = p.w;
    }

    if (j == 0) P[0] = make_float4(1.0f, 0.0f, 0.0f, 1.0f);
    #pragma unroll
    for (int mi = 0; mi < 8; ++mi) {
        int g = base + mi + 1;      // P index this slot produces
        if (g < T) {
            M2 r = mmul(S[mi], Bm);
            P[g] = make_float4(r.a, r.b, r.c, r.d);
        }
    }
}

// ---------------- Kernel 1: out[n] = P_n @ x0 ----------------
// 2 consecutive rows per block; each x0 column-group loaded once, emits 4
// float4 stores (2 per row). 4096 blocks x 256 threads, plain stores.
__global__ __launch_bounds__(256) void out_kernel(const float4* __restrict__ P,
                                                  const float* __restrict__ x0,
                                                  float* __restrict__ out,
                                                  int B, int T) {
    const int q = B >> 2;                            // float4 groups per x-row
    const float4* xr0 = (const float4*)x0;           // row 0 of x0
    const float4* xr1 = xr0 + q;                     // row 1 of x0
    const int n0 = blockIdx.x * 2;
    const int n1 = n0 + 1;
    const bool has1 = (n1 < T);

    const float4 p0 = P[n0];
    const float4 p1 = has1 ? P[n1] : p0;

    float4* o0 = (float4*)(out + (size_t)n0 * (size_t)(2 * B));
    float4* o1 = (float4*)(out + (size_t)n1 * (size_t)(2 * B));

    for (int g = threadIdx.x; g < q; g += 256) {
        float4 u = xr0[g];
        float4 v = xr1[g];
        float4 r;

        r.x = p0.x * u.x + p0.y * v.x;
        r.y = p0.x * u.y + p0.y * v.y;
        r.z = p0.x * u.z + p0.y * v.z;
        r.w = p0.x * u.w + p0.y * v.w;
        o0[g] = r;
        r.x = p0.z * u.x + p0.w * v.x;
        r.y = p0.z * u.y + p0.w * v.y;
        r.z = p0.z * u.z + p0.w * v.z;
        r.w = p0.z * u.w + p0.w * v.w;
        o0[q + g] = r;

        if (has1) {
            r.x = p1.x * u.x + p1.y * v.x;
            r.y = p1.x * u.y + p1.y * v.y;
            r.z = p1.x * u.z + p1.y * v.z;
            r.w = p1.x * u.w + p1.y * v.w;
            o1[g] = r;
            r.x = p1.z * u.x + p1.w * v.x;
            r.y = p1.z * u.y + p1.w * v.y;
            r.z = p1.z * u.z + p1.w * v.z;
            r.w = p1.z * u.w + p1.w * v.w;
            o1[q + g] = r;
        }
    }
}

extern "C" void kernel_launch(void* const* d_in, const int* in_sizes, int n_in,
                              void* d_out, int out_size, void* d_ws, size_t ws_size,
                              hipStream_t stream) {
    const float* t   = (const float*)d_in[0];
    const float* x0  = (const float*)d_in[1];
    const float* w2  = (const float*)d_in[2];
    const float* g0  = (const float*)d_in[3];
    const float* ga  = (const float*)d_in[4];
    const float* wd  = (const float*)d_in[5];
    const int*   uc  = (const int*)d_in[6];

    const int T = in_sizes[0];          // 8192
    const int B = in_sizes[1] / 2;      // 4096

    float4* P = (float4*)d_ws;          // T float4 (128 KB)
    float* out = (float*)d_out;

    escan_kernel<<<1, 1024, 0, stream>>>(t, w2, g0, ga, wd, uc, P, T);
    out_kernel<<<(T + 1) / 2, 256, 0, stream>>>(P, x0, out, B, T);
}

// Round 9
// 278.602 us; speedup vs baseline: 1.0767x; 1.0202x over previous
//
#include <hip/hip_runtime.h>

// Magnus2: x_{n+1} = E_n x_n with a shared 2x2 E_n across the batch.
// v4: no single-CU scan, no P round-trip.
//   Kernel A (4 blocks x 256): chunk products C_j = E_{8j+7}...E_{8j} (1024 chunks).
//   Kernel B (out, 4096 blocks x 256): each block derives P_{n0}, P_{n0+1} itself:
//     masked ordered tree-reduce of C (LDS, 8 rounds) -> exclusive chunk prefix Q,
//     in-chunk partial (<=7 build_E) computed by lane 255 CONCURRENTLY with tree,
//     then the store-bound 2-row write (identical to verified v3 loop).

struct M2 { float a, b, c, d; };

__device__ __forceinline__ M2 mmul(const M2& X, const M2& Y) {
    // X * Y (X applied after Y)
    M2 r;
    r.a = X.a * Y.a + X.b * Y.c;
    r.b = X.a * Y.b + X.b * Y.d;
    r.c = X.c * Y.a + X.d * Y.c;
    r.d = X.c * Y.b + X.d * Y.d;
    return r;
}

__device__ __forceinline__ M2 ident() { M2 r; r.a = 1.f; r.b = 0.f; r.c = 0.f; r.d = 1.f; return r; }
__device__ __forceinline__ float4 m2f4(const M2& m) { return make_float4(m.a, m.b, m.c, m.d); }
__device__ __forceinline__ M2 f4m2(const float4& v) { M2 m; m.a = v.x; m.b = v.y; m.c = v.z; m.d = v.w; return m; }

// Build E_n exactly as the verified kernels did.
__device__ __forceinline__ M2 build_E(const float* __restrict__ t, int n,
                                      float w2, float g0, float ga, float wd,
                                      int uc) {
    float t0 = t[n], t1 = t[n + 1];
    float dt = t1 - t0;
    float tm = t0 + dt * 0.5f;

    float gam0 = g0 * (1.0f + ga * sinf(wd * t0));
    float gamm = g0 * (1.0f + ga * sinf(wd * tm));
    float gam1 = g0 * (1.0f + ga * sinf(wd * t1));

    // Omega = A_mid*dt (+ dt^2/12 * [A0,A1]); [A0,A1] = [[0,d],[w2*d,0]], d=g0-g1
    float Oa = 0.0f;
    float Ob = dt;
    float Oc = -w2 * dt;
    float Od = -gamm * dt;
    if (uc) {
        float k = dt * dt * (1.0f / 12.0f);
        float del = gam0 - gam1;
        Ob += k * del;
        Oc += k * (w2 * del);
    }

    // expm of 2x2
    float m   = 0.5f * (Oa + Od);
    float det = Oa * Od - Ob * Oc;
    float delta = m * m - det;
    float s = sqrtf(fabsf(delta));
    bool pos = delta >= 0.0f;
    bool small_ = s < 1e-6f;
    float s_safe = small_ ? 1.0f : s;
    float cosl = pos ? coshf(s) : cosf(s);
    float sn   = pos ? sinhf(s_safe) : sinf(s_safe);
    float sinch = small_ ? 1.0f : sn / s_safe;
    float em = expf(m);

    M2 E;
    E.a = em * (cosl + sinch * (Oa - m));
    E.b = em * (sinch * Ob);
    E.c = em * (sinch * Oc);
    E.d = em * (cosl + sinch * (Od - m));
    return E;
}

// ---------------- Kernel A: chunk products (fully parallel) ----------------
// C_j = E_{8j+7} ... E_{8j}, identity-padded for k >= T-1. NC = 1024 for T=8192.
__global__ void chunk_kernel(const float* __restrict__ t,
                             const float* __restrict__ p_w2,
                             const float* __restrict__ p_g0,
                             const float* __restrict__ p_ga,
                             const float* __restrict__ p_wd,
                             const int* __restrict__ p_uc,
                             float4* __restrict__ C, int T, int NC) {
    int j = blockIdx.x * blockDim.x + threadIdx.x;
    if (j >= NC) return;
    float w2 = *p_w2, g0 = *p_g0, ga = *p_ga, wd = *p_wd;
    int uc = *p_uc;

    int base = j * 8;
    M2 S = ident();
    #pragma unroll
    for (int mi = 0; mi < 8; ++mi) {
        int k = base + mi;
        if (k < T - 1) S = mmul(build_E(t, k, w2, g0, ga, wd, uc), S);
    }
    C[j] = m2f4(S);
}

// ---------------- Kernel B: out[n] = P_n @ x0, P derived per block ----------
// Requires NC <= 1024 (T <= 8193).
__global__ __launch_bounds__(256) void out_kernel(const float* __restrict__ t,
                                                  const float* __restrict__ p_w2,
                                                  const float* __restrict__ p_g0,
                                                  const float* __restrict__ p_ga,
                                                  const float* __restrict__ p_wd,
                                                  const int* __restrict__ p_uc,
                                                  const float4* __restrict__ C,
                                                  const float* __restrict__ x0,
                                                  float* __restrict__ out,
                                                  int B, int T) {
    __shared__ float4 red[256];
    __shared__ float4 aux[2];

    const int tid = threadIdx.x;
    const int n0 = blockIdx.x * 2;
    const int n1 = n0 + 1;
    const bool has1 = (n1 < T);
    const int cj = n0 >> 3;       // chunk containing row n0
    const int r0 = n0 & 7;        // in-chunk offset (even)

    // lane 255 (wave 3): in-chunk partial W = E_{8cj+r0-1}...E_{8cj} and
    // Elast = E_{8cj+r0}; runs concurrently with the tree below.
    if (tid == 255) {
        float w2 = *p_w2, g0 = *p_g0, ga = *p_ga, wd = *p_wd;
        int uc = *p_uc;
        int base = cj * 8;
        M2 W = ident();
        for (int i = 0; i < r0; ++i) W = mmul(build_E(t, base + i, w2, g0, ga, wd, uc), W);
        M2 El = ident();
        if (has1) El = build_E(t, base + r0, w2, g0, ga, wd, uc);
        aux[0] = m2f4(W);
        aux[1] = m2f4(El);
    }

    // masked local product of 4 chunks (newer-on-left), identity for k >= cj
    {
        int k0 = tid * 4;
        M2 L = ident();
        #pragma unroll
        for (int l = 0; l < 4; ++l) {
            int k = k0 + l;
            if (k < cj) L = mmul(f4m2(C[k]), L);
        }
        red[tid] = m2f4(L);
    }
    __syncthreads();

    // ordered tree reduction: red[0] = L_255 x ... x L_0 = C_{cj-1}...C_0 = Q
    for (int s = 128; s > 0; s >>= 1) {
        if (tid < s) red[tid] = m2f4(mmul(f4m2(red[tid + s]), f4m2(red[tid])));
        __syncthreads();
    }

    if (tid == 0) {
        M2 Q  = f4m2(red[0]);
        M2 W  = f4m2(aux[0]);
        M2 El = f4m2(aux[1]);
        M2 P0 = mmul(W, Q);        // P_{n0}
        M2 P1 = mmul(El, P0);      // P_{n0+1}
        red[0] = m2f4(P0);
        red[1] = m2f4(P1);
    }
    __syncthreads();

    const float4 p0 = red[0];
    const float4 p1 = red[1];

    // store-bound 2-row write (identical to verified v3 loop)
    const int q = B >> 2;                            // float4 groups per x-row
    const float4* xr0 = (const float4*)x0;           // row 0 of x0
    const float4* xr1 = xr0 + q;                     // row 1 of x0
    float4* o0 = (float4*)(out + (size_t)n0 * (size_t)(2 * B));
    float4* o1 = (float4*)(out + (size_t)n1 * (size_t)(2 * B));

    for (int g = tid; g < q; g += 256) {
        float4 u = xr0[g];
        float4 v = xr1[g];
        float4 r;

        r.x = p0.x * u.x + p0.y * v.x;
        r.y = p0.x * u.y + p0.y * v.y;
        r.z = p0.x * u.z + p0.y * v.z;
        r.w = p0.x * u.w + p0.y * v.w;
        o0[g] = r;
        r.x = p0.z * u.x + p0.w * v.x;
        r.y = p0.z * u.y + p0.w * v.y;
        r.z = p0.z * u.z + p0.w * v.z;
        r.w = p0.z * u.w + p0.w * v.w;
        o0[q + g] = r;

        if (has1) {
            r.x = p1.x * u.x + p1.y * v.x;
            r.y = p1.x * u.y + p1.y * v.y;
            r.z = p1.x * u.z + p1.y * v.z;
            r.w = p1.x * u.w + p1.y * v.w;
            o1[g] = r;
            r.x = p1.z * u.x + p1.w * v.x;
            r.y = p1.z * u.y + p1.w * v.y;
            r.z = p1.z * u.z + p1.w * v.z;
            r.w = p1.z * u.w + p1.w * v.w;
            o1[q + g] = r;
        }
    }
}

extern "C" void kernel_launch(void* const* d_in, const int* in_sizes, int n_in,
                              void* d_out, int out_size, void* d_ws, size_t ws_size,
                              hipStream_t stream) {
    const float* t   = (const float*)d_in[0];
    const float* x0  = (const float*)d_in[1];
    const float* w2  = (const float*)d_in[2];
    const float* g0  = (const float*)d_in[3];
    const float* ga  = (const float*)d_in[4];
    const float* wd  = (const float*)d_in[5];
    const int*   uc  = (const int*)d_in[6];

    const int T = in_sizes[0];          // 8192
    const int B = in_sizes[1] / 2;      // 4096

    const int NC = (T - 1 + 7) / 8;     // 1024 chunks
    float4* C = (float4*)d_ws;          // NC float4 (16 KB)
    float* out = (float*)d_out;

    chunk_kernel<<<(NC + 255) / 256, 256, 0, stream>>>(t, w2, g0, ga, wd, uc, C, T, NC);
    out_kernel<<<(T + 1) / 2, 256, 0, stream>>>(t, w2, g0, ga, wd, uc, C, x0, out, B, T);
}